// Round 9
// baseline (484.528 us; speedup 1.0000x reference)
//
#include <hip/hip_runtime.h>
#include <hip/hip_bf16.h>
#include <math.h>

#define N_NODES 20000
#define F_INN 512
#define HH 64
#define NLAYERS 8
#define E_EDGES 640000
#define COUT 40
#define ECAP 800016   // padded CSR capacity: sum ceil(deg/8)*8 <= E + 7*N = 780000

typedef __bf16 bf16x8 __attribute__((ext_vector_type(8)));
typedef float f32x4 __attribute__((ext_vector_type(4)));
typedef unsigned short us8 __attribute__((ext_vector_type(8)));

__device__ __forceinline__ unsigned short f2bf(float f) {
    unsigned int u = __builtin_bit_cast(unsigned int, f);
    u += 0x7FFFu + ((u >> 16) & 1u);   // RNE
    return (unsigned short)(u >> 16);
}
__device__ __forceinline__ float bf2f(unsigned short s) {
    unsigned int u = ((unsigned int)s) << 16;
    return __builtin_bit_cast(float, u);
}
__device__ __forceinline__ float i2f(int s) { return __builtin_bit_cast(float, s); }

// Swizzled-tile fragment load (MFMA 16x16x32 bf16). Tile [rows][64k] bf16,
// element (r,k) at r*64 + ((k>>3)^(r&7))*8 + (k&7).
__device__ __forceinline__ us8 ldfrag(const unsigned short* tile, int row, int ks, int lane) {
    int slot = ks * 4 + (lane >> 4);
    int off = row * 64 + ((slot ^ (row & 7)) << 3);
    return *(const us8*)(tile + off);
}

__device__ __forceinline__ f32x4 mfma16(us8 a, us8 b, f32x4 c) {
    return __builtin_amdgcn_mfma_f32_16x16x32_bf16(
        __builtin_bit_cast(bf16x8, a), __builtin_bit_cast(bf16x8, b), c, 0, 0, 0);
}

// ---------------- CSR build ----------------
__global__ __launch_bounds__(256) void k_hist(const int* __restrict__ row, int* __restrict__ cnt) {
    int e = blockIdx.x * 256 + threadIdx.x;
    if (e < E_EDGES) atomicAdd(&cnt[row[e]], 1);
}

__global__ __launch_bounds__(1024) void k_scan(const int* __restrict__ cnt, int* __restrict__ row_start,
                                               int* __restrict__ cursor) {
    __shared__ int sd[1024];
    int t = threadIdx.x;
    int local[20];
    int s = 0;
    int base = t * 20;
#pragma unroll
    for (int i = 0; i < 20; i++) {
        int idx = base + i;
        int v = (idx < N_NODES) ? ((cnt[idx] + 7) & ~7) : 0;   // pad rows to x8
        local[i] = v; s += v;
    }
    sd[t] = s;
    __syncthreads();
    for (int d = 1; d < 1024; d <<= 1) {
        int v = (t >= d) ? sd[t - d] : 0;
        __syncthreads();
        sd[t] += v;
        __syncthreads();
    }
    int run = sd[t] - s;
#pragma unroll
    for (int i = 0; i < 20; i++) {
        int idx = base + i;
        if (idx < N_NODES) { row_start[idx] = run; cursor[idx] = run; run += local[i]; }
    }
    if (t == 1023) row_start[N_NODES] = sd[1023];
}

__global__ __launch_bounds__(256) void k_scatter(const int* __restrict__ row, const int* __restrict__ col,
                                                 const float* __restrict__ ewin, int* __restrict__ cursor,
                                                 int2* __restrict__ epk) {
    int e = blockIdx.x * 256 + threadIdx.x;
    if (e < E_EDGES) {
        int r = row[e];
        int p = atomicAdd(&cursor[r], 1);
        int2 v;
        v.x = col[e];
        v.y = __builtin_bit_cast(int, ewin[e]);
        epk[p] = v;
    }
}

// ---------------- weight prep ----------------
__global__ __launch_bounds__(256) void k_w0t(const float* __restrict__ w0, unsigned short* __restrict__ w0t) {
    int idx = blockIdx.x * 256 + threadIdx.x;  // 32768
    if (idx < F_INN * HH) {
        int k = idx >> 6, f = idx & 63;
        w0t[f * 512 + (((k >> 3) ^ (f & 7)) << 3) + (k & 7)] = f2bf(w0[idx]);
    }
}
__global__ __launch_bounds__(256) void k_wt(const float* __restrict__ w1, unsigned short* __restrict__ wt) {
    int idx = blockIdx.x * 256 + threadIdx.x;  // 163840
    if (idx < HH * HH * COUT) {
        int klin = idx / 40;
        int c = idx - klin * 40;
        int i = klin >> 6, j = klin & 63;
        wt[c * 4096 + i * 64 + (((j >> 3) ^ (i & 7)) << 3) + (j & 7)] = f2bf(w1[idx]);
    }
}
// Wf[l][k][c] = beta_l*conv_w[l][k][c] + (k==c)*(1-beta_l), f32 (no transpose)
__global__ __launch_bounds__(256) void k_wprep(const float* __restrict__ convw, float* __restrict__ Wf) {
    int idx = blockIdx.x * 256 + threadIdx.x;  // 8*4096
    if (idx < NLAYERS * HH * HH) {
        int l = idx >> 12;
        int k = (idx >> 6) & 63, c = idx & 63;
        float beta = logf(0.5f / (float)(l + 1) + 1.0f);
        Wf[idx] = beta * convw[idx] + ((k == c) ? (1.0f - beta) : 0.0f);
    }
}

// ---------------- lin0: h0 = relu(x @ W0 + b0), MFMA bf16, bf16 out ----------------
__global__ __launch_bounds__(256) void k_lin0(const float* __restrict__ x, const unsigned short* __restrict__ w0t,
                                              const float* __restrict__ b0, unsigned short* __restrict__ h0b) {
    __shared__ __align__(16) unsigned short As[32 * 64];
    __shared__ __align__(16) unsigned short Bs[64 * 64];
    const int t = threadIdx.x;
    const int w = t >> 6, lane = t & 63;
    const int r0 = blockIdx.x * 32;
    const int rA = t >> 3, g = t & 7;
    f32x4 acc[2] = {};
    for (int kc = 0; kc < 8; kc++) {
        if (kc) __syncthreads();
        {
            const float* src = x + (size_t)(r0 + rA) * F_INN + kc * 64 + g * 8;
            float4 f0 = *(const float4*)src;
            float4 f1 = *(const float4*)(src + 4);
            us8 v;
            v[0] = f2bf(f0.x); v[1] = f2bf(f0.y); v[2] = f2bf(f0.z); v[3] = f2bf(f0.w);
            v[4] = f2bf(f1.x); v[5] = f2bf(f1.y); v[6] = f2bf(f1.z); v[7] = f2bf(f1.w);
            *(us8*)(As + rA * 64 + ((g ^ (rA & 7)) << 3)) = v;
        }
        {
            const int4* bsrc = (const int4*)w0t;
            int4* bdst = (int4*)Bs;
#pragma unroll
            for (int i = 0; i < 2; i++) {
                int flat = t * 2 + i;
                int f = flat >> 3, u = flat & 7;
                bdst[f * 8 + u] = bsrc[f * 64 + kc * 8 + u];
            }
        }
        __syncthreads();
#pragma unroll
        for (int ks = 0; ks < 2; ks++) {
            us8 b = ldfrag(Bs, w * 16 + (lane & 15), ks, lane);
            us8 a0 = ldfrag(As, (lane & 15), ks, lane);
            us8 a1 = ldfrag(As, 16 + (lane & 15), ks, lane);
            acc[0] = mfma16(a0, b, acc[0]);
            acc[1] = mfma16(a1, b, acc[1]);
        }
    }
    const int colc = w * 16 + (lane & 15);
    float bias = b0[colc];
#pragma unroll
    for (int mf = 0; mf < 2; mf++) {
#pragma unroll
        for (int reg = 0; reg < 4; reg++) {
            int rowg = r0 + mf * 16 + ((lane >> 4) << 2) + reg;
            h0b[(size_t)rowg * HH + colc] = f2bf(fmaxf(acc[mf][reg] + bias, 0.f));
        }
    }
}

// ---------------- fused layer: pipelined bf16 gather-spmm + residual + matvec(W') + relu ----------------
__global__ __launch_bounds__(256) void k_layer(const unsigned short* __restrict__ hp,
                                               const unsigned short* __restrict__ h0,
                                               unsigned short* __restrict__ hn, const float* __restrict__ W,
                                               const int* __restrict__ rs, const int2* __restrict__ epk) {
    __shared__ float Wl[4096];
    __shared__ float rowbuf[4][64];
    const int t = threadIdx.x;
#pragma unroll
    for (int i = 0; i < 16; i++) Wl[t + i * 256] = W[t + i * 256];
    __syncthreads();
    const int w = t >> 6, lane = t & 63;
    const int r = blockIdx.x * 4 + w;
    const int e0 = rs[r], e1 = rs[r + 1];
    float acc = 0.f;
    if (e0 < e1) {
        // software pipeline: chunk P's gathers in flight while loading chunk Q,
        // so 16 gathers outstanding in steady state (latency-bound fix).
        int4 Pa, Pb, Pc, Pd;
        unsigned short p0, p1, p2, p3, p4, p5, p6, p7;
        int e = e0;
        Pa = *(const int4*)(epk + e);
        Pb = *(const int4*)(epk + e + 2);
        Pc = *(const int4*)(epk + e + 4);
        Pd = *(const int4*)(epk + e + 6);
        p0 = hp[(size_t)Pa.x * HH + lane];
        p1 = hp[(size_t)Pa.z * HH + lane];
        p2 = hp[(size_t)Pb.x * HH + lane];
        p3 = hp[(size_t)Pb.z * HH + lane];
        p4 = hp[(size_t)Pc.x * HH + lane];
        p5 = hp[(size_t)Pc.z * HH + lane];
        p6 = hp[(size_t)Pd.x * HH + lane];
        p7 = hp[(size_t)Pd.z * HH + lane];
        e += 8;
        while (e < e1) {
            int4 Qa = *(const int4*)(epk + e);
            int4 Qb = *(const int4*)(epk + e + 2);
            int4 Qc = *(const int4*)(epk + e + 4);
            int4 Qd = *(const int4*)(epk + e + 6);
            unsigned short q0 = hp[(size_t)Qa.x * HH + lane];
            unsigned short q1 = hp[(size_t)Qa.z * HH + lane];
            unsigned short q2 = hp[(size_t)Qb.x * HH + lane];
            unsigned short q3 = hp[(size_t)Qb.z * HH + lane];
            unsigned short q4 = hp[(size_t)Qc.x * HH + lane];
            unsigned short q5 = hp[(size_t)Qc.z * HH + lane];
            unsigned short q6 = hp[(size_t)Qd.x * HH + lane];
            unsigned short q7 = hp[(size_t)Qd.z * HH + lane];
            e += 8;
            acc += i2f(Pa.y) * bf2f(p0);
            acc += i2f(Pa.w) * bf2f(p1);
            acc += i2f(Pb.y) * bf2f(p2);
            acc += i2f(Pb.w) * bf2f(p3);
            acc += i2f(Pc.y) * bf2f(p4);
            acc += i2f(Pc.w) * bf2f(p5);
            acc += i2f(Pd.y) * bf2f(p6);
            acc += i2f(Pd.w) * bf2f(p7);
            Pa = Qa; Pb = Qb; Pc = Qc; Pd = Qd;
            p0 = q0; p1 = q1; p2 = q2; p3 = q3;
            p4 = q4; p5 = q5; p6 = q6; p7 = q7;
        }
        acc += i2f(Pa.y) * bf2f(p0);
        acc += i2f(Pa.w) * bf2f(p1);
        acc += i2f(Pb.y) * bf2f(p2);
        acc += i2f(Pb.w) * bf2f(p3);
        acc += i2f(Pc.y) * bf2f(p4);
        acc += i2f(Pc.w) * bf2f(p5);
        acc += i2f(Pd.y) * bf2f(p6);
        acc += i2f(Pd.w) * bf2f(p7);
    }
    float outv = 0.9f * acc + 0.1f * bf2f(h0[(size_t)r * HH + lane]);
    rowbuf[w][lane] = outv;
    float t0 = 0.f, t1 = 0.f, t2 = 0.f, t3 = 0.f;   // 4 partials: break serial FMA chain
    const float* rb = rowbuf[w];
#pragma unroll
    for (int k = 0; k < 64; k += 4) {
        float4 o = *(const float4*)(rb + k);
        float s0 = o.x * Wl[(k + 0) * 64 + lane] + o.y * Wl[(k + 1) * 64 + lane];
        float s1 = o.z * Wl[(k + 2) * 64 + lane] + o.w * Wl[(k + 3) * 64 + lane];
        if ((k & 4) == 0) { t0 += s0; t1 += s1; } else { t2 += s0; t3 += s1; }
    }
    float tmp = (t0 + t2) + (t1 + t3);
    hn[(size_t)r * HH + lane] = f2bf(fmaxf(tmp, 0.f));
}

// ---------------- final quadratic form: q[n,c] = h^T M_c h via MFMA ----------------
__global__ __launch_bounds__(256) void k_qform(const unsigned short* __restrict__ hb,
                                               const unsigned short* __restrict__ wt,
                                               float* __restrict__ q) {
    __shared__ __align__(16) unsigned short As[32 * 64];
    __shared__ __align__(16) unsigned short Bs[4 * 64 * 64];
    int t = threadIdx.x;
    int w = t >> 6, lane = t & 63;
    int r0 = blockIdx.x * 32;
    int cbase = blockIdx.y * 4;
    {   // stage A: h tile [32 x 64] bf16, swizzle (straight 16B copies)
        int rA = t >> 3, g = t & 7;
        us8 v = *(const us8*)(hb + (size_t)(r0 + rA) * HH + g * 8);
        *(us8*)(As + rA * 64 + ((g ^ (rA & 7)) << 3)) = v;
    }
    {
        const int4* bsrc = (const int4*)(wt + (size_t)(cbase + w) * 4096);
        int4* bdst = (int4*)(Bs + w * 4096);
#pragma unroll
        for (int i = 0; i < 8; i++) bdst[i * 64 + lane] = bsrc[i * 64 + lane];
    }
    __syncthreads();
    f32x4 acc[2][4] = {};
#pragma unroll
    for (int ks = 0; ks < 2; ks++) {
        us8 a0 = ldfrag(As, (lane & 15), ks, lane);
        us8 a1 = ldfrag(As, 16 + (lane & 15), ks, lane);
#pragma unroll
        for (int nf = 0; nf < 4; nf++) {
            us8 b = ldfrag(Bs + w * 4096, nf * 16 + (lane & 15), ks, lane);
            acc[0][nf] = mfma16(a0, b, acc[0][nf]);
            acc[1][nf] = mfma16(a1, b, acc[1][nf]);
        }
    }
#pragma unroll
    for (int mf = 0; mf < 2; mf++) {
#pragma unroll
        for (int reg = 0; reg < 4; reg++) {
            int rt = mf * 16 + ((lane >> 4) << 2) + reg;
            float v = 0.f;
#pragma unroll
            for (int nf = 0; nf < 4; nf++) {
                int k = nf * 16 + (lane & 15);
                float hb2 = bf2f(As[rt * 64 + (((k >> 3) ^ (rt & 7)) << 3) + (k & 7)]);
                v += acc[mf][nf][reg] * hb2;
            }
            v += __shfl_xor(v, 1);
            v += __shfl_xor(v, 2);
            v += __shfl_xor(v, 4);
            v += __shfl_xor(v, 8);
            if ((lane & 15) == 0) q[(size_t)(r0 + rt) * COUT + cbase + w] = v;
        }
    }
}

// ---------------- finalize ----------------
__global__ __launch_bounds__(256) void k_final(const unsigned short* __restrict__ hb, const float* __restrict__ q,
                                               const float* __restrict__ b1, float* __restrict__ out) {
    int t = threadIdx.x;
    int w = t >> 6, lane = t & 63;
    int r = blockIdx.x * 4 + w;
    float hv = bf2f(hb[(size_t)r * HH + lane]);
    float s = hv * hv;
#pragma unroll
    for (int o = 1; o < 64; o <<= 1) s += __shfl_xor(s, o);
    const float maxn = 1.0f - 4e-3f;
    float scale1 = (s > maxn) ? (maxn / s) : 1.f;
    float pn = fmaxf(s * scale1, 1e-15f);
    float tt = atanhf(fminf(pn, 1.f - 1e-7f));
    float gam = (tt / pn) * scale1;
    float z = 0.f;
    if (lane < COUT) z = gam * q[(size_t)r * COUT + lane] + b1[lane];
    float un2 = z * z;
#pragma unroll
    for (int o = 1; o < 64; o <<= 1) un2 += __shfl_xor(un2, o);
    float un = fmaxf(sqrtf(un2), 1e-15f);
    float th = tanhf(un);
    float fac = fminf(th, maxn) / un;
    float f = z * fac;
    float m = (lane < COUT) ? f : -1e30f;
#pragma unroll
    for (int o = 1; o < 64; o <<= 1) m = fmaxf(m, __shfl_xor(m, o));
    float ex = (lane < COUT) ? __expf(f - m) : 0.f;
    float se = ex;
#pragma unroll
    for (int o = 1; o < 64; o <<= 1) se += __shfl_xor(se, o);
    if (lane < COUT) out[(size_t)r * COUT + lane] = f - m - logf(se);
}

extern "C" void kernel_launch(void* const* d_in, const int* in_sizes, int n_in,
                              void* d_out, int out_size, void* d_ws, size_t ws_size,
                              hipStream_t stream) {
    (void)in_sizes; (void)n_in; (void)out_size; (void)ws_size;
    const float* x = (const float*)d_in[0];
    const int* row = (const int*)d_in[1];
    const int* col = (const int*)d_in[2];
    const float* eww = (const float*)d_in[3];
    const float* w0 = (const float*)d_in[4];
    const float* b0 = (const float*)d_in[5];
    const float* convw = (const float*)d_in[6];
    const float* w1 = (const float*)d_in[7];
    const float* b1 = (const float*)d_in[8];
    float* out = (float*)d_out;

    char* ws = (char*)d_ws;
    unsigned short* h0b = (unsigned short*)(ws + 0);        // 2,560,000
    unsigned short* hAb = (unsigned short*)(ws + 2560000);  // 2,560,000
    unsigned short* hBb = (unsigned short*)(ws + 5120000);  // 2,560,000
    float* q  = (float*)(ws + 7680000);                     // 3,200,000
    int* rs   = (int*)(ws + 10880000);                      // 80,016
    int* cur  = (int*)(ws + 10960016);                      // 80,000
    int2* epk = (int2*)(ws + 11040016);                     // ECAP*8 = 6,400,128
    unsigned short* w0t = (unsigned short*)(ws + 17440144);  // 65,536
    unsigned short* wt  = (unsigned short*)(ws + 17505680);  // 327,680
    float* Wf = (float*)(ws + 17833360);                     // 131,072 -> end ~18.0 MB

    hipMemsetAsync(cur, 0, N_NODES * sizeof(int), stream);
    hipMemsetAsync(epk, 0, (size_t)ECAP * 8, stream);
    k_hist<<<2500, 256, 0, stream>>>(row, cur);
    k_scan<<<1, 1024, 0, stream>>>(cur, rs, cur);
    k_scatter<<<2500, 256, 0, stream>>>(row, col, eww, cur, epk);
    k_w0t<<<128, 256, 0, stream>>>(w0, w0t);
    k_wt<<<640, 256, 0, stream>>>(w1, wt);
    k_wprep<<<128, 256, 0, stream>>>(convw, Wf);
    k_lin0<<<625, 256, 0, stream>>>(x, w0t, b0, h0b);

    const unsigned short* hp = h0b;
    unsigned short* hn = hAb;
    for (int l = 0; l < NLAYERS; l++) {
        k_layer<<<5000, 256, 0, stream>>>(hp, h0b, hn, Wf + l * 4096, rs, epk);
        hp = hn;
        hn = (hn == hAb) ? hBb : hAb;
    }
    k_qform<<<dim3(625, 10), 256, 0, stream>>>(hp, wt, q);
    k_final<<<5000, 256, 0, stream>>>(hp, q, b1, out);
}

// Round 12
// 434.479 us; speedup vs baseline: 1.1152x; 1.1152x over previous
//
#include <hip/hip_runtime.h>
#include <hip/hip_bf16.h>
#include <math.h>

#define N_NODES 20000
#define F_INN 512
#define HH 64
#define NLAYERS 8
#define E_EDGES 640000
#define COUT 40
#define ECAP 800016   // padded CSR capacity: sum ceil(deg/8)*8 <= E + 7*N = 780000

typedef __bf16 bf16x8 __attribute__((ext_vector_type(8)));
typedef float f32x4 __attribute__((ext_vector_type(4)));
typedef unsigned short us8 __attribute__((ext_vector_type(8)));

__device__ __forceinline__ unsigned short f2bf(float f) {
    unsigned int u = __builtin_bit_cast(unsigned int, f);
    u += 0x7FFFu + ((u >> 16) & 1u);   // RNE
    return (unsigned short)(u >> 16);
}
__device__ __forceinline__ float bf2f(unsigned short s) {
    unsigned int u = ((unsigned int)s) << 16;
    return __builtin_bit_cast(float, u);
}
__device__ __forceinline__ float i2f(int s) { return __builtin_bit_cast(float, s); }

// Swizzled-tile fragment load (MFMA 16x16x32 bf16). Tile [rows][64k] bf16,
// element (r,k) at r*64 + ((k>>3)^(r&7))*8 + (k&7).
__device__ __forceinline__ us8 ldfrag(const unsigned short* tile, int row, int ks, int lane) {
    int slot = ks * 4 + (lane >> 4);
    int off = row * 64 + ((slot ^ (row & 7)) << 3);
    return *(const us8*)(tile + off);
}

__device__ __forceinline__ f32x4 mfma16(us8 a, us8 b, f32x4 c) {
    return __builtin_amdgcn_mfma_f32_16x16x32_bf16(
        __builtin_bit_cast(bf16x8, a), __builtin_bit_cast(bf16x8, b), c, 0, 0, 0);
}

// ---------------- CSR build ----------------
__global__ __launch_bounds__(256) void k_hist(const int* __restrict__ row, int* __restrict__ cnt) {
    int e = blockIdx.x * 256 + threadIdx.x;
    if (e < E_EDGES) atomicAdd(&cnt[row[e]], 1);
}

__global__ __launch_bounds__(1024) void k_scan(const int* __restrict__ cnt, int* __restrict__ row_start,
                                               int* __restrict__ cursor) {
    __shared__ int sd[1024];
    int t = threadIdx.x;
    int local[20];
    int s = 0;
    int base = t * 20;
#pragma unroll
    for (int i = 0; i < 20; i++) {
        int idx = base + i;
        int v = (idx < N_NODES) ? ((cnt[idx] + 7) & ~7) : 0;   // pad rows to x8
        local[i] = v; s += v;
    }
    sd[t] = s;
    __syncthreads();
    for (int d = 1; d < 1024; d <<= 1) {
        int v = (t >= d) ? sd[t - d] : 0;
        __syncthreads();
        sd[t] += v;
        __syncthreads();
    }
    int run = sd[t] - s;
#pragma unroll
    for (int i = 0; i < 20; i++) {
        int idx = base + i;
        if (idx < N_NODES) { row_start[idx] = run; cursor[idx] = run; run += local[i]; }
    }
    if (t == 1023) row_start[N_NODES] = sd[1023];
}

__global__ __launch_bounds__(256) void k_scatter(const int* __restrict__ row, const int* __restrict__ col,
                                                 const float* __restrict__ ewin, int* __restrict__ cursor,
                                                 unsigned long long* __restrict__ epk) {
    int e = blockIdx.x * 256 + threadIdx.x;
    if (e < E_EDGES) {
        int r = row[e];
        int p = atomicAdd(&cursor[r], 1);
        unsigned long long v = (unsigned long long)(unsigned int)col[e]
            | ((unsigned long long)__builtin_bit_cast(unsigned int, ewin[e]) << 32);
        __builtin_nontemporal_store(v, epk + p);   // nt: bypass L2, kill cross-XCD line bounce
    }
}

// ---------------- merged weight prep ----------------
// blocks [0,128): w0t   [128,768): wt   [768,896): Wf
__global__ __launch_bounds__(256) void k_prep(const float* __restrict__ w0, unsigned short* __restrict__ w0t,
                                              const float* __restrict__ w1, unsigned short* __restrict__ wt,
                                              const float* __restrict__ convw, float* __restrict__ Wf) {
    int b = blockIdx.x;
    int t = threadIdx.x;
    if (b < 128) {
        int idx = b * 256 + t;             // 32768 = F_INN*HH
        int k = idx >> 6, f = idx & 63;
        w0t[f * 512 + (((k >> 3) ^ (f & 7)) << 3) + (k & 7)] = f2bf(w0[idx]);
    } else if (b < 768) {
        int idx = (b - 128) * 256 + t;     // 163840 = HH*HH*COUT
        int klin = idx / 40;
        int c = idx - klin * 40;
        int i = klin >> 6, j = klin & 63;
        wt[c * 4096 + i * 64 + (((j >> 3) ^ (i & 7)) << 3) + (j & 7)] = f2bf(w1[idx]);
    } else {
        int idx = (b - 768) * 256 + t;     // 32768 = NLAYERS*HH*HH
        int l = idx >> 12;
        int k = (idx >> 6) & 63, c = idx & 63;
        float beta = logf(0.5f / (float)(l + 1) + 1.0f);
        Wf[idx] = beta * convw[idx] + ((k == c) ? (1.0f - beta) : 0.0f);
    }
}

// ---------------- lin0: h0 = relu(x @ W0 + b0), MFMA bf16, bf16 out ----------------
__global__ __launch_bounds__(256) void k_lin0(const float* __restrict__ x, const unsigned short* __restrict__ w0t,
                                              const float* __restrict__ b0, unsigned short* __restrict__ h0b) {
    __shared__ __align__(16) unsigned short As[32 * 64];
    __shared__ __align__(16) unsigned short Bs[64 * 64];
    const int t = threadIdx.x;
    const int w = t >> 6, lane = t & 63;
    const int r0 = blockIdx.x * 32;
    const int rA = t >> 3, g = t & 7;
    f32x4 acc[2] = {};
    for (int kc = 0; kc < 8; kc++) {
        if (kc) __syncthreads();
        {
            const float* src = x + (size_t)(r0 + rA) * F_INN + kc * 64 + g * 8;
            float4 f0 = *(const float4*)src;
            float4 f1 = *(const float4*)(src + 4);
            us8 v;
            v[0] = f2bf(f0.x); v[1] = f2bf(f0.y); v[2] = f2bf(f0.z); v[3] = f2bf(f0.w);
            v[4] = f2bf(f1.x); v[5] = f2bf(f1.y); v[6] = f2bf(f1.z); v[7] = f2bf(f1.w);
            *(us8*)(As + rA * 64 + ((g ^ (rA & 7)) << 3)) = v;
        }
        {
            const int4* bsrc = (const int4*)w0t;
            int4* bdst = (int4*)Bs;
#pragma unroll
            for (int i = 0; i < 2; i++) {
                int flat = t * 2 + i;
                int f = flat >> 3, u = flat & 7;
                bdst[f * 8 + u] = bsrc[f * 64 + kc * 8 + u];
            }
        }
        __syncthreads();
#pragma unroll
        for (int ks = 0; ks < 2; ks++) {
            us8 b = ldfrag(Bs, w * 16 + (lane & 15), ks, lane);
            us8 a0 = ldfrag(As, (lane & 15), ks, lane);
            us8 a1 = ldfrag(As, 16 + (lane & 15), ks, lane);
            acc[0] = mfma16(a0, b, acc[0]);
            acc[1] = mfma16(a1, b, acc[1]);
        }
    }
    const int colc = w * 16 + (lane & 15);
    float bias = b0[colc];
#pragma unroll
    for (int mf = 0; mf < 2; mf++) {
#pragma unroll
        for (int reg = 0; reg < 4; reg++) {
            int rowg = r0 + mf * 16 + ((lane >> 4) << 2) + reg;
            h0b[(size_t)rowg * HH + colc] = f2bf(fmaxf(acc[mf][reg] + bias, 0.f));
        }
    }
}

// ---------------- fused layer: bf16 gather-spmm + residual + matvec(W') + relu (R4-exact) ----------------
__global__ __launch_bounds__(256) void k_layer(const unsigned short* __restrict__ hp,
                                               const unsigned short* __restrict__ h0,
                                               unsigned short* __restrict__ hn, const float* __restrict__ W,
                                               const int* __restrict__ rs, const int2* __restrict__ epk) {
    __shared__ float Wl[4096];
    __shared__ float rowbuf[4][64];
    const int t = threadIdx.x;
#pragma unroll
    for (int i = 0; i < 16; i++) Wl[t + i * 256] = W[t + i * 256];
    __syncthreads();
    const int w = t >> 6, lane = t & 63;
    const int r = blockIdx.x * 4 + w;
    const int e0 = rs[r], e1 = rs[r + 1];
    float acc = 0.f;
    int e = e0;
    if (e < e1) {
        int4 a = *(const int4*)(epk + e);
        int4 b = *(const int4*)(epk + e + 2);
        int4 c = *(const int4*)(epk + e + 4);
        int4 d = *(const int4*)(epk + e + 6);
        for (;;) {
            int4 A = a, B = b, C = c, D = d;
            int en = e + 8;
            bool more = en < e1;
            if (more) {
                a = *(const int4*)(epk + en);
                b = *(const int4*)(epk + en + 2);
                c = *(const int4*)(epk + en + 4);
                d = *(const int4*)(epk + en + 6);
            }
            acc += i2f(A.y) * bf2f(hp[(size_t)A.x * HH + lane]);
            acc += i2f(A.w) * bf2f(hp[(size_t)A.z * HH + lane]);
            acc += i2f(B.y) * bf2f(hp[(size_t)B.x * HH + lane]);
            acc += i2f(B.w) * bf2f(hp[(size_t)B.z * HH + lane]);
            acc += i2f(C.y) * bf2f(hp[(size_t)C.x * HH + lane]);
            acc += i2f(C.w) * bf2f(hp[(size_t)C.z * HH + lane]);
            acc += i2f(D.y) * bf2f(hp[(size_t)D.x * HH + lane]);
            acc += i2f(D.w) * bf2f(hp[(size_t)D.z * HH + lane]);
            if (!more) break;
            e = en;
        }
    }
    float outv = 0.9f * acc + 0.1f * bf2f(h0[(size_t)r * HH + lane]);
    rowbuf[w][lane] = outv;
    float tmp = 0.f;
    const float* rb = rowbuf[w];
#pragma unroll
    for (int k = 0; k < 64; k += 4) {
        float4 o = *(const float4*)(rb + k);
        tmp += o.x * Wl[(k + 0) * 64 + lane];
        tmp += o.y * Wl[(k + 1) * 64 + lane];
        tmp += o.z * Wl[(k + 2) * 64 + lane];
        tmp += o.w * Wl[(k + 3) * 64 + lane];
    }
    hn[(size_t)r * HH + lane] = f2bf(fmaxf(tmp, 0.f));
}

// ---------------- final quadratic form: q[n,c] = h^T M_c h via MFMA ----------------
__global__ __launch_bounds__(256) void k_qform(const unsigned short* __restrict__ hb,
                                               const unsigned short* __restrict__ wt,
                                               float* __restrict__ q) {
    __shared__ __align__(16) unsigned short As[32 * 64];
    __shared__ __align__(16) unsigned short Bs[4 * 64 * 64];
    int t = threadIdx.x;
    int w = t >> 6, lane = t & 63;
    int r0 = blockIdx.x * 32;
    int cbase = blockIdx.y * 4;
    {   // stage A: h tile [32 x 64] bf16, swizzle (straight 16B copies)
        int rA = t >> 3, g = t & 7;
        us8 v = *(const us8*)(hb + (size_t)(r0 + rA) * HH + g * 8);
        *(us8*)(As + rA * 64 + ((g ^ (rA & 7)) << 3)) = v;
    }
    {
        const int4* bsrc = (const int4*)(wt + (size_t)(cbase + w) * 4096);
        int4* bdst = (int4*)(Bs + w * 4096);
#pragma unroll
        for (int i = 0; i < 8; i++) bdst[i * 64 + lane] = bsrc[i * 64 + lane];
    }
    __syncthreads();
    f32x4 acc[2][4] = {};
#pragma unroll
    for (int ks = 0; ks < 2; ks++) {
        us8 a0 = ldfrag(As, (lane & 15), ks, lane);
        us8 a1 = ldfrag(As, 16 + (lane & 15), ks, lane);
#pragma unroll
        for (int nf = 0; nf < 4; nf++) {
            us8 b = ldfrag(Bs + w * 4096, nf * 16 + (lane & 15), ks, lane);
            acc[0][nf] = mfma16(a0, b, acc[0][nf]);
            acc[1][nf] = mfma16(a1, b, acc[1][nf]);
        }
    }
#pragma unroll
    for (int mf = 0; mf < 2; mf++) {
#pragma unroll
        for (int reg = 0; reg < 4; reg++) {
            int rt = mf * 16 + ((lane >> 4) << 2) + reg;
            float v = 0.f;
#pragma unroll
            for (int nf = 0; nf < 4; nf++) {
                int k = nf * 16 + (lane & 15);
                float hb2 = bf2f(As[rt * 64 + (((k >> 3) ^ (rt & 7)) << 3) + (k & 7)]);
                v += acc[mf][nf][reg] * hb2;
            }
            v += __shfl_xor(v, 1);
            v += __shfl_xor(v, 2);
            v += __shfl_xor(v, 4);
            v += __shfl_xor(v, 8);
            if ((lane & 15) == 0) q[(size_t)(r0 + rt) * COUT + cbase + w] = v;
        }
    }
}

// ---------------- finalize ----------------
__global__ __launch_bounds__(256) void k_final(const unsigned short* __restrict__ hb, const float* __restrict__ q,
                                               const float* __restrict__ b1, float* __restrict__ out) {
    int t = threadIdx.x;
    int w = t >> 6, lane = t & 63;
    int r = blockIdx.x * 4 + w;
    float hv = bf2f(hb[(size_t)r * HH + lane]);
    float s = hv * hv;
#pragma unroll
    for (int o = 1; o < 64; o <<= 1) s += __shfl_xor(s, o);
    const float maxn = 1.0f - 4e-3f;
    float scale1 = (s > maxn) ? (maxn / s) : 1.f;
    float pn = fmaxf(s * scale1, 1e-15f);
    float tt = atanhf(fminf(pn, 1.f - 1e-7f));
    float gam = (tt / pn) * scale1;
    float z = 0.f;
    if (lane < COUT) z = gam * q[(size_t)r * COUT + lane] + b1[lane];
    float un2 = z * z;
#pragma unroll
    for (int o = 1; o < 64; o <<= 1) un2 += __shfl_xor(un2, o);
    float un = fmaxf(sqrtf(un2), 1e-15f);
    float th = tanhf(un);
    float fac = fminf(th, maxn) / un;
    float f = z * fac;
    float m = (lane < COUT) ? f : -1e30f;
#pragma unroll
    for (int o = 1; o < 64; o <<= 1) m = fmaxf(m, __shfl_xor(m, o));
    float ex = (lane < COUT) ? __expf(f - m) : 0.f;
    float se = ex;
#pragma unroll
    for (int o = 1; o < 64; o <<= 1) se += __shfl_xor(se, o);
    if (lane < COUT) out[(size_t)r * COUT + lane] = f - m - logf(se);
}

extern "C" void kernel_launch(void* const* d_in, const int* in_sizes, int n_in,
                              void* d_out, int out_size, void* d_ws, size_t ws_size,
                              hipStream_t stream) {
    (void)in_sizes; (void)n_in; (void)out_size; (void)ws_size;
    const float* x = (const float*)d_in[0];
    const int* row = (const int*)d_in[1];
    const int* col = (const int*)d_in[2];
    const float* eww = (const float*)d_in[3];
    const float* w0 = (const float*)d_in[4];
    const float* b0 = (const float*)d_in[5];
    const float* convw = (const float*)d_in[6];
    const float* w1 = (const float*)d_in[7];
    const float* b1 = (const float*)d_in[8];
    float* out = (float*)d_out;

    char* ws = (char*)d_ws;
    unsigned short* h0b = (unsigned short*)(ws + 0);        // 2,560,000
    unsigned short* hAb = (unsigned short*)(ws + 2560000);  // 2,560,000
    unsigned short* hBb = (unsigned short*)(ws + 5120000);  // 2,560,000
    float* q  = (float*)(ws + 7680000);                     // 3,200,000
    int* rs   = (int*)(ws + 10880000);                      // 80,016
    int* cur  = (int*)(ws + 10960016);                      // 80,000
    int2* epk = (int2*)(ws + 11040016);                     // ECAP*8 = 6,400,128
    unsigned short* w0t = (unsigned short*)(ws + 17440144);  // 65,536
    unsigned short* wt  = (unsigned short*)(ws + 17505680);  // 327,680
    float* Wf = (float*)(ws + 17833360);                     // 131,072 -> end ~18.0 MB

    hipMemsetAsync(cur, 0, N_NODES * sizeof(int), stream);
    hipMemsetAsync(epk, 0, (size_t)ECAP * 8, stream);
    k_hist<<<2500, 256, 0, stream>>>(row, cur);
    k_scan<<<1, 1024, 0, stream>>>(cur, rs, cur);
    k_scatter<<<2500, 256, 0, stream>>>(row, col, eww, cur, (unsigned long long*)epk);
    k_prep<<<896, 256, 0, stream>>>(w0, w0t, w1, wt, convw, Wf);
    k_lin0<<<625, 256, 0, stream>>>(x, w0t, b0, h0b);

    const unsigned short* hp = h0b;
    unsigned short* hn = hAb;
    for (int l = 0; l < NLAYERS; l++) {
        k_layer<<<5000, 256, 0, stream>>>(hp, h0b, hn, Wf + l * 4096, rs, epk);
        hp = hn;
        hn = (hn == hAb) ? hBb : hAb;
    }
    k_qform<<<dim3(625, 10), 256, 0, stream>>>(hp, wt, q);
    k_final<<<5000, 256, 0, stream>>>(hp, q, b1, out);
}